// Round 11
// baseline (450.652 us; speedup 1.0000x reference)
//
#include <hip/hip_runtime.h>
#include <hip/hip_bf16.h>

#define DIM 64
#define NREL 8
#define KS 512              // Sx width (k-permuted: k = ch*8 + r)
#define KTOT 576            // GEMM K: 512 + 64 root

typedef __bf16 bf16x8 __attribute__((ext_vector_type(8)));
typedef __bf16 bf16x4 __attribute__((ext_vector_type(4)));
typedef float  f32x4  __attribute__((ext_vector_type(4)));

// ---------------- fused: hist (rank-returning, 4-way ILP) + gather + sentinels ----------------
__global__ __launch_bounds__(256) void histgather_kernel(const int* __restrict__ dst,
                                                         const int* __restrict__ et,
                                                         int* __restrict__ deg8,
                                                         int* __restrict__ eoff,
                                                         const int* __restrict__ x_idx,
                                                         const float* __restrict__ emb,
                                                         __bf16* __restrict__ xb0,
                                                         __bf16* __restrict__ xb1,
                                                         int* __restrict__ srcs,
                                                         int N, int E, int epad_cap) {
    int i = blockIdx.x * 256 + threadIdx.x;
    if (i < N * DIM) {
        int n = i >> 6;
        int c = i & 63;
        xb0[i] = (__bf16)emb[(size_t)x_idx[n] * DIM + c];
    }
    if (i < DIM) {                                        // sentinel zero rows (index N)
        xb0[(size_t)N * DIM + i] = (__bf16)0.f;
        xb1[(size_t)N * DIM + i] = (__bf16)0.f;
    }
    if (i < epad_cap) srcs[i] = N;                        // padding -> sentinel
    // 4 strided edge streams per thread -> 4 independent atomics in flight
    int quarter = (E + 3) >> 2;
    if (i < quarter) {
        int i0 = i, i1 = i + quarter, i2 = i + 2 * quarter, i3 = i + 3 * quarter;
        bool h1 = i1 < E, h2 = i2 < E, h3 = i3 < E;
        int c0 = dst[i0] * 8 + et[i0];
        int c1 = h1 ? dst[i1] * 8 + et[i1] : 0;
        int c2 = h2 ? dst[i2] * 8 + et[i2] : 0;
        int c3 = h3 ? dst[i3] * 8 + et[i3] : 0;
        int o0 = atomicAdd(&deg8[c0], 1);
        int o1 = h1 ? atomicAdd(&deg8[c1], 1) : 0;
        int o2 = h2 ? atomicAdd(&deg8[c2], 1) : 0;
        int o3 = h3 ? atomicAdd(&deg8[c3], 1) : 0;
        eoff[i0] = o0;
        if (h1) eoff[i1] = o1;
        if (h2) eoff[i2] = o2;
        if (h3) eoff[i3] = o3;
    }
}

// ---------------- scan1 over per-dst PADDED totals + invdeg (true deg) ----------------
__global__ __launch_bounds__(256) void scan1_kernel(const int* __restrict__ deg8,
                                                    int* __restrict__ offs,
                                                    int* __restrict__ bsum,
                                                    float* __restrict__ invdeg, int N) {
    __shared__ int sd[256];
    int tid = threadIdx.x;
    int d = blockIdx.x * 256 + tid;
    int vpad = 0;
    if (d < N) {
        int vtrue = 0;
#pragma unroll
        for (int r = 0; r < NREL; ++r) {
            int dv = deg8[d * 8 + r];
            vtrue += dv;
            vpad += (dv + 3) & ~3;
        }
        invdeg[d] = 1.0f / fmaxf((float)vtrue, 1.0f);
    }
    sd[tid] = vpad;
    __syncthreads();
#pragma unroll
    for (int off = 1; off < 256; off <<= 1) {
        int t = (tid >= off) ? sd[tid - off] : 0;
        __syncthreads();
        sd[tid] += t;
        __syncthreads();
    }
    if (d < N) offs[d] = sd[tid] - vpad;
    if (tid == 255) bsum[blockIdx.x] = sd[255];
}

// ---------------- scan2 (block 0) + wcat (blocks >= 1) fused ----------------
// Wt[l][c][k]: k<512 -> k=ch*8+r maps weight[l][r][ch][c]; k>=512 -> root[l][k-512][c]
__global__ __launch_bounds__(512) void scan2wcat_kernel(int* __restrict__ bsum, int nb,
                                                        const float* __restrict__ weight,
                                                        const float* __restrict__ root,
                                                        __bf16* __restrict__ Wt, int L) {
    if (blockIdx.x == 0) {
        __shared__ int sd[512];
        int tid = threadIdx.x;
        int v = (tid < nb) ? bsum[tid] : 0;
        sd[tid] = v;
        __syncthreads();
#pragma unroll
        for (int off = 1; off < 512; off <<= 1) {
            int t = (tid >= off) ? sd[tid - off] : 0;
            __syncthreads();
            sd[tid] += t;
            __syncthreads();
        }
        if (tid < nb) bsum[tid] = sd[tid] - v;
    } else {
        int idx = (blockIdx.x - 1) * 512 + threadIdx.x;
        int total = L * 64 * KTOT;
        if (idx >= total) return;
        int l = idx / (64 * KTOT);
        int rem = idx - l * 64 * KTOT;
        int c = rem / KTOT;
        int k = rem - c * KTOT;
        float w;
        if (k < KS) {
            int ch = k >> 3, r = k & 7;
            w = weight[(((l * 8 + r) * 64) + ch) * 64 + c];
        } else {
            w = root[(l * 64 + (k - KS)) * 64 + c];
        }
        Wt[idx] = (__bf16)w;
    }
}

// ---------------- rp_pad build (padded per-cell starts) ----------------
__global__ __launch_bounds__(256) void rpbuild_kernel(const int* __restrict__ deg8,
                                                      const int* __restrict__ offs,
                                                      const int* __restrict__ bsum,
                                                      int* __restrict__ rp,
                                                      int N) {
    int d = blockIdx.x * 256 + threadIdx.x;
    if (d >= N) return;
    int base = offs[d] + bsum[blockIdx.x];
    int run = 0;
#pragma unroll
    for (int r = 0; r < NREL; ++r) {
        rp[d * 8 + r] = base + run;
        run += (deg8[d * 8 + r] + 3) & ~3;
    }
    if (d == N - 1) rp[(size_t)N * 8] = base + run;   // E_pad total
}

// ---------------- bucket: atomic-free scatter, 4 coalesced strided streams per thread
__global__ __launch_bounds__(256) void bucket_kernel(const int* __restrict__ src,
                                                     const int* __restrict__ dst,
                                                     const int* __restrict__ et,
                                                     const int* __restrict__ rp,
                                                     const int* __restrict__ eoff,
                                                     int* __restrict__ srcs, int E) {
    int i = blockIdx.x * 256 + threadIdx.x;
    int quarter = (E + 3) >> 2;
    if (i >= quarter) return;
    int i1 = i + quarter, i2 = i + 2 * quarter, i3 = i + 3 * quarter;
    bool h1 = i1 < E, h2 = i2 < E, h3 = i3 < E;
    int c0 = dst[i] * 8 + et[i];
    int c1 = h1 ? dst[i1] * 8 + et[i1] : 0;
    int c2 = h2 ? dst[i2] * 8 + et[i2] : 0;
    int c3 = h3 ? dst[i3] * 8 + et[i3] : 0;
    int r0 = rp[c0];
    int r1 = h1 ? rp[c1] : 0;
    int r2 = h2 ? rp[c2] : 0;
    int r3 = h3 ? rp[c3] : 0;
    int o0 = eoff[i];
    int o1 = h1 ? eoff[i1] : 0;
    int o2 = h2 ? eoff[i2] : 0;
    int o3 = h3 ? eoff[i3] : 0;
    int s0 = src[i];
    int s1 = h1 ? src[i1] : 0;
    int s2 = h2 ? src[i2] : 0;
    int s3 = h3 ? src[i3] : 0;
    srcs[r0 + o0] = s0;
    if (h1) srcs[r1 + o1] = s1;
    if (h2) srcs[r2 + o2] = s2;
    if (h3) srcs[r3 + o3] = s3;
}

// ---------------- aggregate v4: wave/dst; per-cell quads; scalar dwordx4 src loads
__global__ __launch_bounds__(256) void aggregate_kernel(const __bf16* __restrict__ xb,
                                                        const int* __restrict__ srcs,
                                                        const int* __restrict__ rp,
                                                        const float* __restrict__ invdeg,
                                                        __bf16* __restrict__ Sx, int N) {
    int d0 = blockIdx.x * 4 + (threadIdx.x >> 6);
    if (d0 >= N) return;
    int d = __builtin_amdgcn_readfirstlane(d0);
    int lane = threadIdx.x & 63;

    int rpv[9];
#pragma unroll
    for (int r = 0; r < 9; ++r) rpv[r] = rp[d * 8 + r];   // scalar loads (uniform)

    float facc[NREL];
#pragma unroll
    for (int r = 0; r < NREL; ++r) {                      // r compile-time -> named acc regs
        float acc = 0.f;
        for (int q = rpv[r]; q < rpv[r + 1]; q += 4) {    // uniform bounds, step 4
            int4 sv = *reinterpret_cast<const int4*>(srcs + q);   // s_load_dwordx4
            float v0 = (float)xb[(size_t)sv.x * DIM + lane];      // 4 independent gathers
            float v1 = (float)xb[(size_t)sv.y * DIM + lane];      // (sentinel N -> zero row)
            float v2 = (float)xb[(size_t)sv.z * DIM + lane];
            float v3 = (float)xb[(size_t)sv.w * DIM + lane];
            acc += (v0 + v1) + (v2 + v3);
        }
        facc[r] = acc;
    }

    float inv = invdeg[d];
    bf16x8 h;
#pragma unroll
    for (int r = 0; r < NREL; ++r) h[r] = (__bf16)(facc[r] * inv);
    // k-permuted row: element k = ch*8 + r, lane stores ch=lane -> 16B contiguous
    *reinterpret_cast<bf16x8*>(Sx + (size_t)d * KS + lane * 8) = h;
}

// ---------------- GEMM v2: W-in-registers (A-operand), Sx streamed (B-operand)
// NOTE: xout MUST NOT alias xin (waves share rows, split channels -> WAR race if in-place).
__global__ __launch_bounds__(256) void gemm_kernel(const __bf16* __restrict__ Sx,
                                                   const __bf16* __restrict__ xin,
                                                   const __bf16* __restrict__ Wt,    // [64][576]
                                                   const float* __restrict__ bias_l, // [64]
                                                   __bf16* __restrict__ xout, int N) {
    int wave = threadIdx.x >> 6;
    int lane = threadIdx.x & 63;
    int l15 = lane & 15;
    int lg  = lane >> 4;

    // hoist A (weights) into registers: 18 x 4 VGPRs = 72 VGPRs
    bf16x8 afrag[KTOT / 32];
    {
        const __bf16* wrow = Wt + (size_t)(16 * wave + l15) * KTOT + lg * 8;
#pragma unroll
        for (int kk = 0; kk < KTOT / 32; ++kk)
            afrag[kk] = *reinterpret_cast<const bf16x8*>(wrow + kk * 32);
    }
    int cbase = 16 * wave + 4 * lg;
    f32x4 bias4 = *reinterpret_cast<const f32x4*>(bias_l + cbase);

    int ntiles = (N + 15) >> 4;
    for (int tile = blockIdx.x; tile < ntiles; tile += gridDim.x) {
        int n = tile * 16 + l15;
        int nc = (n < N) ? n : (N - 1);                   // clamped load, guarded store
        const __bf16* srow = Sx  + (size_t)nc * KS  + lg * 8;
        const __bf16* xrow = xin + (size_t)nc * DIM + lg * 8;

        f32x4 acc = (f32x4){0.f, 0.f, 0.f, 0.f};
#pragma unroll
        for (int kk = 0; kk < KS / 32; ++kk) {
            bf16x8 bv = *reinterpret_cast<const bf16x8*>(srow + kk * 32);
            acc = __builtin_amdgcn_mfma_f32_16x16x32_bf16(afrag[kk], bv, acc, 0, 0, 0);
        }
#pragma unroll
        for (int kk = 0; kk < DIM / 32; ++kk) {
            bf16x8 bv = *reinterpret_cast<const bf16x8*>(xrow + kk * 32);
            acc = __builtin_amdgcn_mfma_f32_16x16x32_bf16(afrag[KS / 32 + kk], bv, acc, 0, 0, 0);
        }

        if (n < N) {
            bf16x4 h;
#pragma unroll
            for (int i = 0; i < 4; ++i)
                h[i] = (__bf16)fmaxf(acc[i] + bias4[i], 0.f);
            *reinterpret_cast<bf16x4*>(xout + (size_t)n * DIM + cbase) = h;
        }
    }
}

// ---------------- score ----------------
__global__ __launch_bounds__(256) void score_kernel(const __bf16* __restrict__ xb,
                                                    const int* __restrict__ s,
                                                    const int* __restrict__ t,
                                                    float* __restrict__ out, int T) {
    int i = blockIdx.x * 4 + (threadIdx.x >> 6);
    if (i >= T) return;
    int lane = threadIdx.x & 63;
    float p = (float)xb[(size_t)s[i] * DIM + lane] * (float)xb[(size_t)t[i] * DIM + lane];
#pragma unroll
    for (int off = 32; off > 0; off >>= 1) p += __shfl_down(p, off, 64);
    if (lane == 0) out[i] = p;
}

extern "C" void kernel_launch(void* const* d_in, const int* in_sizes, int n_in,
                              void* d_out, int out_size, void* d_ws, size_t ws_size,
                              hipStream_t stream) {
    const int*   x_idx  = (const int*)d_in[0];
    const int*   eidx   = (const int*)d_in[1];   // [2,E]
    const int*   etyp   = (const int*)d_in[2];   // [E]
    const int*   tidx   = (const int*)d_in[3];   // [2,T]
    const float* emb    = (const float*)d_in[4]; // [N,64]
    const float* weight = (const float*)d_in[5]; // [L,8,64,64]
    const float* root   = (const float*)d_in[6]; // [L,64,64]
    const float* bias   = (const float*)d_in[7]; // [L,64]

    int N = in_sizes[0];
    int E = in_sizes[2];
    int T = in_sizes[3] / 2;
    int L = in_sizes[5] / (NREL * DIM * DIM);

    const int* src = eidx;
    const int* dst = eidx + E;
    const int* ts  = tidx;
    const int* tt  = tidx + T;
    float* out = (float*)d_out;

    int epad_cap = E + 3 * N * NREL + 64;   // worst-case padded edge count

    // ---- workspace carve-up ----
    char* p = (char*)d_ws;
    auto alloc = [&](size_t bytes) -> void* {
        void* r = (void*)p;
        p += (bytes + 255) & ~(size_t)255;
        return r;
    };
    __bf16* Sx      = (__bf16*)alloc((size_t)N * KS * sizeof(__bf16));
    __bf16* xb0     = (__bf16*)alloc((size_t)(N + 1) * DIM * sizeof(__bf16));  // +1 zero row
    __bf16* xb1     = (__bf16*)alloc((size_t)(N + 1) * DIM * sizeof(__bf16));  // ping-pong
    __bf16* Wt      = (__bf16*)alloc((size_t)L * 64 * KTOT * sizeof(__bf16));
    int*    srcs    = (int*)   alloc((size_t)epad_cap * sizeof(int));
    int*    eoff    = (int*)   alloc((size_t)E * sizeof(int));
    int*    deg8    = (int*)   alloc((size_t)N * 8 * sizeof(int));
    int*    rp      = (int*)   alloc(((size_t)N * 8 + 1) * sizeof(int));
    int*    offs    = (int*)   alloc((size_t)N * sizeof(int));
    float*  invdeg  = (float*) alloc((size_t)N * sizeof(float));
    int*    bsum    = (int*)   alloc(1024 * sizeof(int));

    int nb = (N + 255) / 256;

    hipMemsetAsync(deg8, 0, (size_t)N * 8 * sizeof(int), stream);
    histgather_kernel<<<((size_t)N * DIM + 255) / 256, 256, 0, stream>>>(
        dst, etyp, deg8, eoff, x_idx, emb, xb0, xb1, srcs, N, E, epad_cap);
    scan1_kernel<<<nb, 256, 0, stream>>>(deg8, offs, bsum, invdeg, N);
    {
        int wtotal = L * 64 * KTOT;
        int wblocks = 1 + (wtotal + 511) / 512;
        scan2wcat_kernel<<<wblocks, 512, 0, stream>>>(bsum, nb, weight, root, Wt, L);
    }
    rpbuild_kernel<<<nb, 256, 0, stream>>>(deg8, offs, bsum, rp, N);
    {
        int quarter = (E + 3) / 4;
        bucket_kernel<<<(quarter + 255) / 256, 256, 0, stream>>>(src, dst, etyp, rp, eoff, srcs, E);
    }

    __bf16* xcur = xb0;
    __bf16* xnxt = xb1;
    for (int l = 0; l < L; ++l) {
        aggregate_kernel<<<(N + 3) / 4, 256, 0, stream>>>(xcur, srcs, rp, invdeg, Sx, N);
        gemm_kernel<<<1024, 256, 0, stream>>>(Sx, xcur,
                                              Wt + (size_t)l * 64 * KTOT,
                                              bias + (size_t)l * DIM,
                                              xnxt, N);
        __bf16* tmp = xcur; xcur = xnxt; xnxt = tmp;
    }

    score_kernel<<<(T + 3) / 4, 256, 0, stream>>>(xcur, ts, tt, out, T);
}